// Round 3
// baseline (550.934 us; speedup 1.0000x reference)
//
#include <hip/hip_runtime.h>

#define BATCH 25
#define LSEQ  11
#define OUTR  4
#define DIM   2048
#define VOCAB 32000
#define KSEL  1024

typedef _Float16 half8  __attribute__((ext_vector_type(8)));
typedef float    floatx4 __attribute__((ext_vector_type(4)));

#define WH_BYTES ((size_t)VOCAB * DIM * 2)

// ---------------- W fp32 -> fp16 (RNE), plain streaming loads ----------------
// 128 elems/thread; grid = VOCAB*DIM/(256*128) = 2000.
// (nontemporal hints removed: L3-residency of wh proven irrelevant to gather
//  time — dispatch with wh fully L3-resident ran at identical 181us — and nt
//  loads were the prime suspect for conv underperformance.)
__global__ __launch_bounds__(256) void conv_f16(const float* __restrict__ w,
                                                _Float16* __restrict__ wh) {
    const size_t base = (size_t)blockIdx.x * (256 * 128) + (size_t)threadIdx.x * 8;
#pragma unroll
    for (int c = 0; c < 16; ++c) {
        const size_t i = base + (size_t)c * (256 * 8);
        const floatx4 a = *(const floatx4*)(w + i);
        const floatx4 b = *(const floatx4*)(w + i + 4);
        half8 hv;
        hv[0] = (_Float16)a[0]; hv[1] = (_Float16)a[1];
        hv[2] = (_Float16)a[2]; hv[3] = (_Float16)a[3];
        hv[4] = (_Float16)b[0]; hv[5] = (_Float16)b[1];
        hv[6] = (_Float16)b[2]; hv[7] = (_Float16)b[3];
        *(half8*)(wh + i) = hv;
    }
}

// ---------------- MFMA gather: out[bl,o,k] = h[bl,o,:] . Wh[idx[bl,k],:] ----
// KPB=128 -> 2200 blocks -> 8 blocks/CU co-resident (32 waves/CU, LDS 135KB).
// Plain unroll-8 loop: round-1-verified 171us, VGPR 36. (Explicit rolling
// prefetch buffers regressed to 181us/VGPR 24 — compiler collapsed them.)
#define TPW 2                 // 16-wide k-tiles per wave
#define KPB (4 * TPW * 16)    // 128 k per block (4 waves)
#define NKC (KSEL / KPB)      // 8 blocks per (b,l)
#define ROWE 2080             // padded LDS row stride in fp16 elems (+64 B pad)

__global__ __launch_bounds__(256) void gather_mfma(
    const float*    __restrict__ h,
    const _Float16* __restrict__ wh,
    const int*      __restrict__ index,
    float*          __restrict__ out)
{
    __shared__ _Float16 hs[OUTR * ROWE];   // 16.25 KiB, padded rows

    const int bl   = blockIdx.x / NKC;
    const int kc   = blockIdx.x % NKC;
    const int tid  = threadIdx.x;
    const int wave = tid >> 6;
    const int lane = tid & 63;
    const int quad = lane >> 4;
    const int n    = lane & 15;            // MFMA column (k within tile)
    const int row  = lane & 3;             // A-row alias (M rows 4-15 duplicate 0-3)

    // ---- stage h[bl] (4x2048 fp32) into LDS as fp16, padded rows ----
    const float* hp = h + (size_t)bl * (OUTR * DIM);
#pragma unroll
    for (int o = 0; o < OUTR; ++o) {
        const int e = o * DIM + tid * 8;
        const floatx4 a = *(const floatx4*)(hp + e);
        const floatx4 b = *(const floatx4*)(hp + e + 4);
        half8 hv;
        hv[0] = (_Float16)a[0]; hv[1] = (_Float16)a[1];
        hv[2] = (_Float16)a[2]; hv[3] = (_Float16)a[3];
        hv[4] = (_Float16)b[0]; hv[5] = (_Float16)b[1];
        hv[6] = (_Float16)b[2]; hv[7] = (_Float16)b[3];
        *(half8*)(hs + o * ROWE + tid * 8) = hv;
    }
    __syncthreads();

    // ---- B row pointers: lane's column n -> gathered W row ----
    const int kb_blk = kc * KPB;
    const _Float16* bptr[TPW];
#pragma unroll
    for (int t = 0; t < TPW; ++t) {
        const int k_id = kb_blk + (wave * TPW + t) * 16 + n;
        const int ridx = index[(size_t)bl * KSEL + k_id];
        bptr[t] = wh + (size_t)ridx * DIM + quad * 8;
    }

    const _Float16* aptr = hs + row * ROWE + quad * 8;

    floatx4 acc[TPW];
#pragma unroll
    for (int t = 0; t < TPW; ++t) acc[t] = (floatx4){0.f, 0.f, 0.f, 0.f};

    // ---- K loop: 64 steps of K=32, deep unroll for MLP ----
#pragma unroll 8
    for (int ks = 0; ks < DIM / 32; ++ks) {
        const half8 a = *(const half8*)(aptr + ks * 32);
        half8 b[TPW];
#pragma unroll
        for (int t = 0; t < TPW; ++t)
            b[t] = *(const half8*)(bptr[t] + ks * 32);
#pragma unroll
        for (int t = 0; t < TPW; ++t)
            acc[t] = __builtin_amdgcn_mfma_f32_16x16x32_f16(a, b[t], acc[t], 0, 0, 0);
    }

    // ---- epilogue: D rows 0-3 live in quad 0 (col=lane&15, row=reg) ----
    if (quad == 0) {
        float* op = out + (size_t)bl * (OUTR * KSEL) + kb_blk;
#pragma unroll
        for (int t = 0; t < TPW; ++t) {
            const int kcol = (wave * TPW + t) * 16 + n;
#pragma unroll
            for (int r = 0; r < OUTR; ++r)
                op[r * KSEL + kcol] = acc[t][r];
        }
    }
}

// ---------------- fallback (fp32 table) ----------------
#define FKPB 64
#define FKPW 16

__global__ __launch_bounds__(256) void ehead_f32_kernel(
    const float* __restrict__ h,
    const float* __restrict__ wt,
    const int*   __restrict__ index,
    float*       __restrict__ out)
{
    const int nkc = KSEL / FKPB;
    const int bl  = blockIdx.x / nkc;
    const int kc  = blockIdx.x % nkc;
    const int kbase = kc * FKPB;

    __shared__ float hsf[OUTR * DIM];
    const float* hp = h + (size_t)bl * (OUTR * DIM);
    const int tid = threadIdx.x;
#pragma unroll
    for (int i = 0; i < (OUTR * DIM) / (256 * 4); ++i) {
        const int e = (i * 256 + tid) * 4;
        *(float4*)&hsf[e] = *(const float4*)&hp[e];
    }
    __syncthreads();

    const int wave = tid >> 6;
    const int lane = tid & 63;
    const int* ip = index + (size_t)bl * KSEL + kbase + wave * FKPW;
    float*     op = out   + (size_t)bl * (OUTR * KSEL) + kbase + wave * FKPW;

    for (int g = 0; g < FKPW; g += 4) {
        const float4* r0 = (const float4*)(wt + (size_t)ip[g + 0] * DIM);
        const float4* r1 = (const float4*)(wt + (size_t)ip[g + 1] * DIM);
        const float4* r2 = (const float4*)(wt + (size_t)ip[g + 2] * DIM);
        const float4* r3 = (const float4*)(wt + (size_t)ip[g + 3] * DIM);
        float acc[OUTR][4];
#pragma unroll
        for (int o = 0; o < OUTR; ++o)
#pragma unroll
            for (int kk = 0; kk < 4; ++kk) acc[o][kk] = 0.f;
#pragma unroll
        for (int c = 0; c < DIM / 256; ++c) {
            const int off = c * 64 + lane;
            const float4 w0 = r0[off];
            const float4 w1 = r1[off];
            const float4 w2 = r2[off];
            const float4 w3 = r3[off];
#pragma unroll
            for (int o = 0; o < OUTR; ++o) {
                const float4 hv = *(const float4*)&hsf[o * DIM + off * 4];
                acc[o][0] += hv.x * w0.x + hv.y * w0.y + hv.z * w0.z + hv.w * w0.w;
                acc[o][1] += hv.x * w1.x + hv.y * w1.y + hv.z * w1.z + hv.w * w1.w;
                acc[o][2] += hv.x * w2.x + hv.y * w2.y + hv.z * w2.z + hv.w * w2.w;
                acc[o][3] += hv.x * w3.x + hv.y * w3.y + hv.z * w3.z + hv.w * w3.w;
            }
        }
#pragma unroll
        for (int o = 0; o < OUTR; ++o)
#pragma unroll
            for (int kk = 0; kk < 4; ++kk) {
                float v = acc[o][kk];
#pragma unroll
                for (int s = 32; s >= 1; s >>= 1) v += __shfl_xor(v, s, 64);
                acc[o][kk] = v;
            }
        if (lane < 16) {
            float v = 0.f;
#pragma unroll
            for (int oo = 0; oo < OUTR; ++oo)
#pragma unroll
                for (int qq = 0; qq < 4; ++qq)
                    v = (oo * 4 + qq == lane) ? acc[oo][qq] : v;
            op[(lane >> 2) * KSEL + g + (lane & 3)] = v;
        }
    }
}

extern "C" void kernel_launch(void* const* d_in, const int* in_sizes, int n_in,
                              void* d_out, int out_size, void* d_ws, size_t ws_size,
                              hipStream_t stream) {
    const float* h   = (const float*)d_in[0];
    const float* wt  = (const float*)d_in[1];
    const int*   idx = (const int*)d_in[2];
    float*       out = (float*)d_out;

    if (ws_size >= WH_BYTES) {
        _Float16* wh = (_Float16*)d_ws;
        conv_f16<<<(VOCAB * DIM) / (256 * 128), 256, 0, stream>>>(wt, wh);
        const int grid = BATCH * LSEQ * NKC;   // 2200 blocks -> 32 waves/CU
        gather_mfma<<<grid, 256, 0, stream>>>(h, wh, idx, out);
    } else {
        const int grid = BATCH * LSEQ * (KSEL / FKPB);
        ehead_f32_kernel<<<grid, 256, 0, stream>>>(h, wt, idx, out);
    }
}

// Round 4
// 540.962 us; speedup vs baseline: 1.0184x; 1.0184x over previous
//
#include <hip/hip_runtime.h>

#define BATCH 25
#define LSEQ  11
#define OUTR  4
#define DIM   2048
#define VOCAB 32000
#define KSEL  1024

typedef _Float16 half8  __attribute__((ext_vector_type(8)));
typedef float    floatx4 __attribute__((ext_vector_type(4)));

#define WH_BYTES ((size_t)VOCAB * DIM * 2)

// ---------------- W fp32 -> fp16 (RNE), pure nontemporal stream --------------
// nt on BOTH sides: reads bypass L3 (proven better r0/r1 vs plain r3), and
// stores skip L3 allocation (gather speed is independent of wh residency --
// r2 dispatch-104: wh fully L3-resident ran identical 181us).
// 128 elems/thread; grid = VOCAB*DIM/(256*128) = 2000.
__global__ __launch_bounds__(256) void conv_f16(const float* __restrict__ w,
                                                _Float16* __restrict__ wh) {
    const size_t base = (size_t)blockIdx.x * (256 * 128) + (size_t)threadIdx.x * 8;
#pragma unroll
    for (int c = 0; c < 16; ++c) {
        const size_t i = base + (size_t)c * (256 * 8);
        const floatx4 a = __builtin_nontemporal_load((const floatx4*)(w + i));
        const floatx4 b = __builtin_nontemporal_load((const floatx4*)(w + i + 4));
        half8 hv;
        hv[0] = (_Float16)a[0]; hv[1] = (_Float16)a[1];
        hv[2] = (_Float16)a[2]; hv[3] = (_Float16)a[3];
        hv[4] = (_Float16)b[0]; hv[5] = (_Float16)b[1];
        hv[6] = (_Float16)b[2]; hv[7] = (_Float16)b[3];
        __builtin_nontemporal_store(hv, (half8*)(wh + i));
    }
}

// ---------------- MFMA gather: out[bl,o,k] = h[bl,o,:] . Wh[idx[bl,k],:] ----
// AT THE MEMORY ROOFLINE: 1.127 GB gathered demand / ~175us = ~6.3 TB/s =
// the chip's achievable fill-fabric ceiling (m13 copy: 6.29 TB/s). Fill rate
// is source-independent (L3-resident wh ran identical speed), line use is
// 100%, bytes irreducible at fp16. Do not touch the K-loop (r2's explicit
// pipeline regressed it: compiler collapsed buffers, VGPR 36->24).
#define TPW 2                 // 16-wide k-tiles per wave
#define KPB (4 * TPW * 16)    // 128 k per block (4 waves)
#define NKC (KSEL / KPB)      // 8 blocks per (b,l)
#define ROWE 2080             // padded LDS row stride in fp16 elems (+64 B pad)

__global__ __launch_bounds__(256) void gather_mfma(
    const float*    __restrict__ h,
    const _Float16* __restrict__ wh,
    const int*      __restrict__ index,
    float*          __restrict__ out)
{
    __shared__ _Float16 hs[OUTR * ROWE];   // 16.25 KiB, padded rows

    const int bl   = blockIdx.x / NKC;
    const int kc   = blockIdx.x % NKC;
    const int tid  = threadIdx.x;
    const int wave = tid >> 6;
    const int lane = tid & 63;
    const int quad = lane >> 4;
    const int n    = lane & 15;            // MFMA column (k within tile)
    const int row  = lane & 3;             // A-row alias (M rows 4-15 duplicate 0-3)

    // ---- stage h[bl] (4x2048 fp32) into LDS as fp16, padded rows ----
    const float* hp = h + (size_t)bl * (OUTR * DIM);
#pragma unroll
    for (int o = 0; o < OUTR; ++o) {
        const int e = o * DIM + tid * 8;
        const floatx4 a = *(const floatx4*)(hp + e);
        const floatx4 b = *(const floatx4*)(hp + e + 4);
        half8 hv;
        hv[0] = (_Float16)a[0]; hv[1] = (_Float16)a[1];
        hv[2] = (_Float16)a[2]; hv[3] = (_Float16)a[3];
        hv[4] = (_Float16)b[0]; hv[5] = (_Float16)b[1];
        hv[6] = (_Float16)b[2]; hv[7] = (_Float16)b[3];
        *(half8*)(hs + o * ROWE + tid * 8) = hv;
    }
    __syncthreads();

    // ---- B row pointers: lane's column n -> gathered W row ----
    const int kb_blk = kc * KPB;
    const _Float16* bptr[TPW];
#pragma unroll
    for (int t = 0; t < TPW; ++t) {
        const int k_id = kb_blk + (wave * TPW + t) * 16 + n;
        const int ridx = index[(size_t)bl * KSEL + k_id];
        bptr[t] = wh + (size_t)ridx * DIM + quad * 8;
    }

    const _Float16* aptr = hs + row * ROWE + quad * 8;

    floatx4 acc[TPW];
#pragma unroll
    for (int t = 0; t < TPW; ++t) acc[t] = (floatx4){0.f, 0.f, 0.f, 0.f};

    // ---- K loop: 64 steps of K=32, deep unroll for MLP ----
#pragma unroll 8
    for (int ks = 0; ks < DIM / 32; ++ks) {
        const half8 a = *(const half8*)(aptr + ks * 32);
        half8 b[TPW];
#pragma unroll
        for (int t = 0; t < TPW; ++t)
            b[t] = *(const half8*)(bptr[t] + ks * 32);
#pragma unroll
        for (int t = 0; t < TPW; ++t)
            acc[t] = __builtin_amdgcn_mfma_f32_16x16x32_f16(a, b[t], acc[t], 0, 0, 0);
    }

    // ---- epilogue: D rows 0-3 live in quad 0 (col=lane&15, row=reg) ----
    if (quad == 0) {
        float* op = out + (size_t)bl * (OUTR * KSEL) + kb_blk;
#pragma unroll
        for (int t = 0; t < TPW; ++t) {
            const int kcol = (wave * TPW + t) * 16 + n;
#pragma unroll
            for (int r = 0; r < OUTR; ++r)
                op[r * KSEL + kcol] = acc[t][r];
        }
    }
}

// ---------------- fallback (fp32 table) ----------------
#define FKPB 64
#define FKPW 16

__global__ __launch_bounds__(256) void ehead_f32_kernel(
    const float* __restrict__ h,
    const float* __restrict__ wt,
    const int*   __restrict__ index,
    float*       __restrict__ out)
{
    const int nkc = KSEL / FKPB;
    const int bl  = blockIdx.x / nkc;
    const int kc  = blockIdx.x % nkc;
    const int kbase = kc * FKPB;

    __shared__ float hsf[OUTR * DIM];
    const float* hp = h + (size_t)bl * (OUTR * DIM);
    const int tid = threadIdx.x;
#pragma unroll
    for (int i = 0; i < (OUTR * DIM) / (256 * 4); ++i) {
        const int e = (i * 256 + tid) * 4;
        *(float4*)&hsf[e] = *(const float4*)&hp[e];
    }
    __syncthreads();

    const int wave = tid >> 6;
    const int lane = tid & 63;
    const int* ip = index + (size_t)bl * KSEL + kbase + wave * FKPW;
    float*     op = out   + (size_t)bl * (OUTR * KSEL) + kbase + wave * FKPW;

    for (int g = 0; g < FKPW; g += 4) {
        const float4* r0 = (const float4*)(wt + (size_t)ip[g + 0] * DIM);
        const float4* r1 = (const float4*)(wt + (size_t)ip[g + 1] * DIM);
        const float4* r2 = (const float4*)(wt + (size_t)ip[g + 2] * DIM);
        const float4* r3 = (const float4*)(wt + (size_t)ip[g + 3] * DIM);
        float acc[OUTR][4];
#pragma unroll
        for (int o = 0; o < OUTR; ++o)
#pragma unroll
            for (int kk = 0; kk < 4; ++kk) acc[o][kk] = 0.f;
#pragma unroll
        for (int c = 0; c < DIM / 256; ++c) {
            const int off = c * 64 + lane;
            const float4 w0 = r0[off];
            const float4 w1 = r1[off];
            const float4 w2 = r2[off];
            const float4 w3 = r3[off];
#pragma unroll
            for (int o = 0; o < OUTR; ++o) {
                const float4 hv = *(const float4*)&hsf[o * DIM + off * 4];
                acc[o][0] += hv.x * w0.x + hv.y * w0.y + hv.z * w0.z + hv.w * w0.w;
                acc[o][1] += hv.x * w1.x + hv.y * w1.y + hv.z * w1.z + hv.w * w1.w;
                acc[o][2] += hv.x * w2.x + hv.y * w2.y + hv.z * w2.z + hv.w * w2.w;
                acc[o][3] += hv.x * w3.x + hv.y * w3.y + hv.z * w3.z + hv.w * w3.w;
            }
        }
#pragma unroll
        for (int o = 0; o < OUTR; ++o)
#pragma unroll
            for (int kk = 0; kk < 4; ++kk) {
                float v = acc[o][kk];
#pragma unroll
                for (int s = 32; s >= 1; s >>= 1) v += __shfl_xor(v, s, 64);
                acc[o][kk] = v;
            }
        if (lane < 16) {
            float v = 0.f;
#pragma unroll
            for (int oo = 0; oo < OUTR; ++oo)
#pragma unroll
                for (int qq = 0; qq < 4; ++qq)
                    v = (oo * 4 + qq == lane) ? acc[oo][qq] : v;
            op[(lane >> 2) * KSEL + g + (lane & 3)] = v;
        }
    }
}

extern "C" void kernel_launch(void* const* d_in, const int* in_sizes, int n_in,
                              void* d_out, int out_size, void* d_ws, size_t ws_size,
                              hipStream_t stream) {
    const float* h   = (const float*)d_in[0];
    const float* wt  = (const float*)d_in[1];
    const int*   idx = (const int*)d_in[2];
    float*       out = (float*)d_out;

    if (ws_size >= WH_BYTES) {
        _Float16* wh = (_Float16*)d_ws;
        conv_f16<<<(VOCAB * DIM) / (256 * 128), 256, 0, stream>>>(wt, wh);
        const int grid = BATCH * LSEQ * NKC;   // 2200 blocks
        gather_mfma<<<grid, 256, 0, stream>>>(h, wh, idx, out);
    } else {
        const int grid = BATCH * LSEQ * (KSEL / FKPB);
        ehead_f32_kernel<<<grid, 256, 0, stream>>>(h, wt, idx, out);
    }
}

// Round 5
// 505.456 us; speedup vs baseline: 1.0900x; 1.0702x over previous
//
#include <hip/hip_runtime.h>

#define BATCH 25
#define LSEQ  11
#define OUTR  4
#define DIM   2048
#define VOCAB 32000
#define KSEL  1024

typedef _Float16 half8  __attribute__((ext_vector_type(8)));
typedef float    floatx4 __attribute__((ext_vector_type(4)));

#define WH_BYTES ((size_t)VOCAB * DIM * 2)

// ---------------- W fp32 -> fp16 (RNE) ----------------
// nt LOADS (w bypasses L3) + PLAIN stores (wh allocates into L3).
// This is the measured-best combination: gather time tracks wh L3-residency
//   r1 (nt-load/plain-store): gather 171us
//   r3 (plain-load: w pollutes L3): 185us
//   r4 (nt-store: wh never in L3): 200us
// wh = 131 MB fits fully in the 256 MB L3; w reads must NOT evict it.
__global__ __launch_bounds__(256) void conv_f16(const float* __restrict__ w,
                                                _Float16* __restrict__ wh) {
    const size_t base = (size_t)blockIdx.x * (256 * 32) + (size_t)threadIdx.x * 8;
#pragma unroll
    for (int c = 0; c < 4; ++c) {
        const size_t i = base + (size_t)c * (256 * 8);
        const floatx4 a = __builtin_nontemporal_load((const floatx4*)(w + i));
        const floatx4 b = __builtin_nontemporal_load((const floatx4*)(w + i + 4));
        half8 hv;
        hv[0] = (_Float16)a[0]; hv[1] = (_Float16)a[1];
        hv[2] = (_Float16)a[2]; hv[3] = (_Float16)a[3];
        hv[4] = (_Float16)b[0]; hv[5] = (_Float16)b[1];
        hv[6] = (_Float16)b[2]; hv[7] = (_Float16)b[3];
        *(half8*)(wh + i) = hv;
    }
}

// ---------------- MFMA gather: out[bl,o,k] = h[bl,o,:] . Wh[idx[bl,k],:] ----
// At a per-CU outstanding-miss x latency wall (~10.7 B/cy/CU through L1):
//   - occupancy 32->58% bought only -7% (r0->r1)
//   - explicit SW pipelining regressed (r2: compiler collapsed buffers)
//   - time tracks wh L3-residency (r1/r3/r4: 171/185/200us) -> latency-bound
//   - FETCH_SIZE constant ~568 MB (~50% L2 hit) in every configuration
// KPB=128 -> 2200 blocks -> 8 blocks/CU (32 waves/CU). Do not touch the
// K-loop: plain unroll-8 is the verified best (171us, VGPR 36).
#define TPW 2                 // 16-wide k-tiles per wave
#define KPB (4 * TPW * 16)    // 128 k per block (4 waves)
#define NKC (KSEL / KPB)      // 8 blocks per (b,l)
#define ROWE 2080             // padded LDS row stride in fp16 elems (+64 B pad)

__global__ __launch_bounds__(256) void gather_mfma(
    const float*    __restrict__ h,
    const _Float16* __restrict__ wh,
    const int*      __restrict__ index,
    float*          __restrict__ out)
{
    __shared__ _Float16 hs[OUTR * ROWE];   // 16.25 KiB, padded rows

    const int bl   = blockIdx.x / NKC;
    const int kc   = blockIdx.x % NKC;
    const int tid  = threadIdx.x;
    const int wave = tid >> 6;
    const int lane = tid & 63;
    const int quad = lane >> 4;
    const int n    = lane & 15;            // MFMA column (k within tile)
    const int row  = lane & 3;             // A-row alias (M rows 4-15 duplicate 0-3)

    // ---- stage h[bl] (4x2048 fp32) into LDS as fp16, padded rows ----
    const float* hp = h + (size_t)bl * (OUTR * DIM);
#pragma unroll
    for (int o = 0; o < OUTR; ++o) {
        const int e = o * DIM + tid * 8;
        const floatx4 a = *(const floatx4*)(hp + e);
        const floatx4 b = *(const floatx4*)(hp + e + 4);
        half8 hv;
        hv[0] = (_Float16)a[0]; hv[1] = (_Float16)a[1];
        hv[2] = (_Float16)a[2]; hv[3] = (_Float16)a[3];
        hv[4] = (_Float16)b[0]; hv[5] = (_Float16)b[1];
        hv[6] = (_Float16)b[2]; hv[7] = (_Float16)b[3];
        *(half8*)(hs + o * ROWE + tid * 8) = hv;
    }
    __syncthreads();

    // ---- B row pointers: lane's column n -> gathered W row ----
    const int kb_blk = kc * KPB;
    const _Float16* bptr[TPW];
#pragma unroll
    for (int t = 0; t < TPW; ++t) {
        const int k_id = kb_blk + (wave * TPW + t) * 16 + n;
        const int ridx = index[(size_t)bl * KSEL + k_id];
        bptr[t] = wh + (size_t)ridx * DIM + quad * 8;
    }

    const _Float16* aptr = hs + row * ROWE + quad * 8;

    floatx4 acc[TPW];
#pragma unroll
    for (int t = 0; t < TPW; ++t) acc[t] = (floatx4){0.f, 0.f, 0.f, 0.f};

    // ---- K loop: 64 steps of K=32, deep unroll for MLP ----
#pragma unroll 8
    for (int ks = 0; ks < DIM / 32; ++ks) {
        const half8 a = *(const half8*)(aptr + ks * 32);
        half8 b[TPW];
#pragma unroll
        for (int t = 0; t < TPW; ++t)
            b[t] = *(const half8*)(bptr[t] + ks * 32);
#pragma unroll
        for (int t = 0; t < TPW; ++t)
            acc[t] = __builtin_amdgcn_mfma_f32_16x16x32_f16(a, b[t], acc[t], 0, 0, 0);
    }

    // ---- epilogue: D rows 0-3 live in quad 0 (col=lane&15, row=reg) ----
    if (quad == 0) {
        float* op = out + (size_t)bl * (OUTR * KSEL) + kb_blk;
#pragma unroll
        for (int t = 0; t < TPW; ++t) {
            const int kcol = (wave * TPW + t) * 16 + n;
#pragma unroll
            for (int r = 0; r < OUTR; ++r)
                op[r * KSEL + kcol] = acc[t][r];
        }
    }
}

// ---------------- fallback (fp32 table) ----------------
#define FKPB 64
#define FKPW 16

__global__ __launch_bounds__(256) void ehead_f32_kernel(
    const float* __restrict__ h,
    const float* __restrict__ wt,
    const int*   __restrict__ index,
    float*       __restrict__ out)
{
    const int nkc = KSEL / FKPB;
    const int bl  = blockIdx.x / nkc;
    const int kc  = blockIdx.x % nkc;
    const int kbase = kc * FKPB;

    __shared__ float hsf[OUTR * DIM];
    const float* hp = h + (size_t)bl * (OUTR * DIM);
    const int tid = threadIdx.x;
#pragma unroll
    for (int i = 0; i < (OUTR * DIM) / (256 * 4); ++i) {
        const int e = (i * 256 + tid) * 4;
        *(float4*)&hsf[e] = *(const float4*)&hp[e];
    }
    __syncthreads();

    const int wave = tid >> 6;
    const int lane = tid & 63;
    const int* ip = index + (size_t)bl * KSEL + kbase + wave * FKPW;
    float*     op = out   + (size_t)bl * (OUTR * KSEL) + kbase + wave * FKPW;

    for (int g = 0; g < FKPW; g += 4) {
        const float4* r0 = (const float4*)(wt + (size_t)ip[g + 0] * DIM);
        const float4* r1 = (const float4*)(wt + (size_t)ip[g + 1] * DIM);
        const float4* r2 = (const float4*)(wt + (size_t)ip[g + 2] * DIM);
        const float4* r3 = (const float4*)(wt + (size_t)ip[g + 3] * DIM);
        float acc[OUTR][4];
#pragma unroll
        for (int o = 0; o < OUTR; ++o)
#pragma unroll
            for (int kk = 0; kk < 4; ++kk) acc[o][kk] = 0.f;
#pragma unroll
        for (int c = 0; c < DIM / 256; ++c) {
            const int off = c * 64 + lane;
            const float4 w0 = r0[off];
            const float4 w1 = r1[off];
            const float4 w2 = r2[off];
            const float4 w3 = r3[off];
#pragma unroll
            for (int o = 0; o < OUTR; ++o) {
                const float4 hv = *(const float4*)&hsf[o * DIM + off * 4];
                acc[o][0] += hv.x * w0.x + hv.y * w0.y + hv.z * w0.z + hv.w * w0.w;
                acc[o][1] += hv.x * w1.x + hv.y * w1.y + hv.z * w1.z + hv.w * w1.w;
                acc[o][2] += hv.x * w2.x + hv.y * w2.y + hv.z * w2.z + hv.w * w2.w;
                acc[o][3] += hv.x * w3.x + hv.y * w3.y + hv.z * w3.z + hv.w * w3.w;
            }
        }
#pragma unroll
        for (int o = 0; o < OUTR; ++o)
#pragma unroll
            for (int kk = 0; kk < 4; ++kk) {
                float v = acc[o][kk];
#pragma unroll
                for (int s = 32; s >= 1; s >>= 1) v += __shfl_xor(v, s, 64);
                acc[o][kk] = v;
            }
        if (lane < 16) {
            float v = 0.f;
#pragma unroll
            for (int oo = 0; oo < OUTR; ++oo)
#pragma unroll
                for (int qq = 0; qq < 4; ++qq)
                    v = (oo * 4 + qq == lane) ? acc[oo][qq] : v;
            op[(lane >> 2) * KSEL + g + (lane & 3)] = v;
        }
    }
}

extern "C" void kernel_launch(void* const* d_in, const int* in_sizes, int n_in,
                              void* d_out, int out_size, void* d_ws, size_t ws_size,
                              hipStream_t stream) {
    const float* h   = (const float*)d_in[0];
    const float* wt  = (const float*)d_in[1];
    const int*   idx = (const int*)d_in[2];
    float*       out = (float*)d_out;

    if (ws_size >= WH_BYTES) {
        _Float16* wh = (_Float16*)d_ws;
        conv_f16<<<(VOCAB * DIM) / (256 * 32), 256, 0, stream>>>(wt, wh);
        const int grid = BATCH * LSEQ * NKC;   // 2200 blocks -> 32 waves/CU
        gather_mfma<<<grid, 256, 0, stream>>>(h, wh, idx, out);
    } else {
        const int grid = BATCH * LSEQ * (KSEL / FKPB);
        ehead_f32_kernel<<<grid, 256, 0, stream>>>(h, wt, idx, out);
    }
}